// Round 6
// baseline (269937.305 us; speedup 1.0000x reference)
//
#include <hip/hip_runtime.h>

#define LSTM_B   4096
#define LSTM_H   1024
#define LSTM_IN  512
#define LSTM_OUT 512
#define CSTRIDE  8192   // u32 stride between counter arrays (32 KB apart)

typedef unsigned long long u64;
typedef unsigned int u32;

__device__ __forceinline__ u32 aload32(const u32* p) {
  return __hip_atomic_load(p, __ATOMIC_RELAXED, __HIP_MEMORY_SCOPE_AGENT);
}
__device__ __forceinline__ void astoref(float* p, float v) {
  __hip_atomic_store((u32*)p, __float_as_uint(v), __ATOMIC_RELAXED, __HIP_MEMORY_SCOPE_AGENT);
}
__device__ __forceinline__ void addrel(u32* p) {
  __hip_atomic_fetch_add(p, 1u, __ATOMIC_RELEASE, __HIP_MEMORY_SCOPE_AGENT);
}
__device__ __forceinline__ float dot4f(float4 a, float4 b) {
  return fmaf(a.x, b.x, fmaf(a.y, b.y, fmaf(a.z, b.z, a.w * b.w)));
}
// fast activations: v_exp_f32 + v_rcp_f32. |rel err| ~1e-6, bounded outputs.
__device__ __forceinline__ float fsig(float x) {
  return __builtin_amdgcn_rcpf(1.0f + __expf(-x));
}
__device__ __forceinline__ float ftanh(float x) {
  return 1.0f - 2.0f * __builtin_amdgcn_rcpf(1.0f + __expf(2.0f * x));
}

// ---- AGPR parking: weights live in the accumulator half of the unified RF.
__device__ __forceinline__ void park4(float4& a, float4 v) {
  asm volatile("v_accvgpr_write_b32 %0, %4\n\t"
               "v_accvgpr_write_b32 %1, %5\n\t"
               "v_accvgpr_write_b32 %2, %6\n\t"
               "v_accvgpr_write_b32 %3, %7"
               : "=a"(a.x), "=a"(a.y), "=a"(a.z), "=a"(a.w)
               : "v"(v.x), "v"(v.y), "v"(v.z), "v"(v.w));
}
__device__ __forceinline__ float4 fetch4(const float4& a) {
  float4 r;
  asm volatile("v_accvgpr_read_b32 %0, %4\n\t"
               "v_accvgpr_read_b32 %1, %5\n\t"
               "v_accvgpr_read_b32 %2, %6\n\t"
               "v_accvgpr_read_b32 %3, %7"
               : "=v"(r.x), "=v"(r.y), "=v"(r.z), "=v"(r.w)
               : "a"(a.x), "a"(a.y), "a"(a.z), "a"(a.w));
  return r;
}

// ---------------- transpose fc_w [512,1024] -> fcwT [1024,512] ----------------
__global__ void k_transpose(const float* __restrict__ w, float* __restrict__ wT) {
  int idx = blockIdx.x * 256 + threadIdx.x;   // 512*1024 total
  int k = idx >> 9;
  int o = idx & 511;
  wT[idx] = w[o * 1024 + k];
}

// ---------------- persistent recurrent kernel ----------------
// 256 blocks x 512 threads (8 autonomous waves, NO barriers, NO LDS).
// Block bx owns hidden units 4bx..4bx+3 of each layer.
// Waves 0-3: layer1 unit j=w (128 weight floats in AGPRs).
// Waves 4-7: layer0 unit j=w-4 (96 weight floats in AGPRs).
// Transport: h0row/h1row are plain fp32 rows; producer lane0 does a relaxed
// agent atomic store of its value, then a RELEASE fetch_add on cnt[class][t].
// Consumers poll 4-8 counter words (<=32B/round), ACQUIRE fence, then bulk
// dwordx4-load the fresh row. The h0 chain (the only serial recurrence) runs
// fully decoupled from layer-1, which trails one step behind.
__global__ __launch_bounds__(512)
__attribute__((amdgpu_waves_per_eu(2, 2)))
void k_recur(
    const float* __restrict__ x,
    const float* __restrict__ Whh0, const float* __restrict__ Wih0,
    const float* __restrict__ bih0, const float* __restrict__ bhh0,
    const float* __restrict__ Wih1, const float* __restrict__ Whh1,
    const float* __restrict__ bih1, const float* __restrict__ bhh1,
    const float* __restrict__ h0in, const float* __restrict__ c0in,
    float* __restrict__ h0row, float* __restrict__ h1row,
    u32* __restrict__ cnt)   // cnt0[j] = cnt + j*CSTRIDE ; cnt1[j] = cnt + (4+j)*CSTRIDE
{
  const int tid = threadIdx.x;           // 0..511
  const int w = tid >> 6, l = tid & 63;
  const int bx = blockIdx.x;
  const int j = w & 3;
  const int hd = 4 * bx + j;

  const u32* c0base = cnt;
  const u32* c1base = cnt + (size_t)4 * CSTRIDE;

  if (w >= 4) {
    // ================= layer-0 waves (the critical chain) =================
    float4 Whr[4][4], Wxr[4][2];  // AGPR-resident
#pragma unroll
    for (int g = 0; g < 4; ++g) {
#pragma unroll
      for (int q = 0; q < 4; ++q)
        park4(Whr[g][q], *(const float4*)&Whh0[(size_t)(g * 1024 + hd) * 1024 + q * 256 + 4 * l]);
#pragma unroll
      for (int q = 0; q < 2; ++q)
        park4(Wxr[g][q], *(const float4*)&Wih0[(size_t)(g * 1024 + hd) * 512 + q * 256 + 4 * l]);
    }
    float bsum[4];
#pragma unroll
    for (int g = 0; g < 4; ++g) bsum[g] = bih0[g * 1024 + hd] + bhh0[g * 1024 + hd];
    float c = c0in[hd];
    u32* myc = cnt + (size_t)j * CSTRIDE;

#pragma unroll 1
    for (int t = 0; t < LSTM_B; ++t) {
      // x(t) fragment: plain loads, issued before the poll so they're in flight
      float4 xa = *(const float4*)&x[(size_t)t * 512 + 4 * l];
      float4 xb = *(const float4*)&x[(size_t)t * 512 + 256 + 4 * l];

      float4 hq[4];
      if (t == 0) {
#pragma unroll
        for (int q = 0; q < 4; ++q) hq[q] = *(const float4*)&h0in[q * 256 + 4 * l];
      } else {
        for (;;) {
          u32 v = 256;
          if (l < 4) v = aload32(&c0base[(size_t)l * CSTRIDE + (t - 1)]);
          if (__all((int)(v >= 256))) break;
          __builtin_amdgcn_s_sleep(1);
        }
        __builtin_amdgcn_fence(__ATOMIC_ACQUIRE, "agent");
#pragma unroll
        for (int q = 0; q < 4; ++q)
          hq[q] = *(const float4*)&h0row[(size_t)(t - 1) * 1024 + q * 256 + 4 * l];
      }

      float a0 = 0.f, a1 = 0.f, a2 = 0.f, a3 = 0.f;
#pragma unroll
      for (int q = 0; q < 4; ++q) {
        { float4 u = fetch4(Whr[0][q]); a0 += dot4f(u, hq[q]); }
        { float4 u = fetch4(Whr[1][q]); a1 += dot4f(u, hq[q]); }
        { float4 u = fetch4(Whr[2][q]); a2 += dot4f(u, hq[q]); }
        { float4 u = fetch4(Whr[3][q]); a3 += dot4f(u, hq[q]); }
      }
      { float4 u = fetch4(Wxr[0][0]); a0 += dot4f(u, xa); u = fetch4(Wxr[0][1]); a0 += dot4f(u, xb); }
      { float4 u = fetch4(Wxr[1][0]); a1 += dot4f(u, xa); u = fetch4(Wxr[1][1]); a1 += dot4f(u, xb); }
      { float4 u = fetch4(Wxr[2][0]); a2 += dot4f(u, xa); u = fetch4(Wxr[2][1]); a2 += dot4f(u, xb); }
      { float4 u = fetch4(Wxr[3][0]); a3 += dot4f(u, xa); u = fetch4(Wxr[3][1]); a3 += dot4f(u, xb); }
#pragma unroll
      for (int m = 1; m < 64; m <<= 1) {
        a0 += __shfl_xor(a0, m, 64);
        a1 += __shfl_xor(a1, m, 64);
        a2 += __shfl_xor(a2, m, 64);
        a3 += __shfl_xor(a3, m, 64);
      }
      c = fsig(a1 + bsum[1]) * c + fsig(a0 + bsum[0]) * ftanh(a2 + bsum[2]);
      float hn = fsig(a3 + bsum[3]) * ftanh(c);
      if (l == 0) {
        astoref(&h0row[(size_t)t * 1024 + hd], hn);
        addrel(&myc[t]);
      }
    }
  } else {
    // ================= layer-1 waves (trail one step behind) =================
    float4 Wi[4][4], Wh[4][4];   // AGPR-resident
#pragma unroll
    for (int g = 0; g < 4; ++g)
#pragma unroll
      for (int q = 0; q < 4; ++q) {
        park4(Wi[g][q], *(const float4*)&Wih1[(size_t)(g * 1024 + hd) * 1024 + q * 256 + 4 * l]);
        park4(Wh[g][q], *(const float4*)&Whh1[(size_t)(g * 1024 + hd) * 1024 + q * 256 + 4 * l]);
      }
    float bsum[4];
#pragma unroll
    for (int g = 0; g < 4; ++g) bsum[g] = bih1[g * 1024 + hd] + bhh1[g * 1024 + hd];
    float c = c0in[1024 + hd];
    u32* myc = cnt + (size_t)(4 + j) * CSTRIDE;

#pragma unroll 1
    for (int t = 0; t < LSTM_B; ++t) {
      // need h0row[t] (cnt0) and h1row[t-1] (cnt1; t=0 -> h1 init from input)
      for (;;) {
        u32 v = 256;
        if (l < 4) v = aload32(&c0base[(size_t)l * CSTRIDE + t]);
        else if (l < 8 && t > 0) v = aload32(&c1base[(size_t)(l - 4) * CSTRIDE + (t - 1)]);
        if (__all((int)(v >= 256))) break;
        __builtin_amdgcn_s_sleep(1);
      }
      __builtin_amdgcn_fence(__ATOMIC_ACQUIRE, "agent");
      float4 h0q[4], h1q[4];
#pragma unroll
      for (int q = 0; q < 4; ++q)
        h0q[q] = *(const float4*)&h0row[(size_t)t * 1024 + q * 256 + 4 * l];
      if (t == 0) {
#pragma unroll
        for (int q = 0; q < 4; ++q) h1q[q] = *(const float4*)&h0in[1024 + q * 256 + 4 * l];
      } else {
#pragma unroll
        for (int q = 0; q < 4; ++q)
          h1q[q] = *(const float4*)&h1row[(size_t)(t - 1) * 1024 + q * 256 + 4 * l];
      }

      float a0 = 0.f, a1 = 0.f, a2 = 0.f, a3 = 0.f;
#pragma unroll
      for (int q = 0; q < 4; ++q) {
        { float4 u = fetch4(Wi[0][q]); a0 += dot4f(u, h0q[q]); u = fetch4(Wh[0][q]); a0 += dot4f(u, h1q[q]); }
        { float4 u = fetch4(Wi[1][q]); a1 += dot4f(u, h0q[q]); u = fetch4(Wh[1][q]); a1 += dot4f(u, h1q[q]); }
        { float4 u = fetch4(Wi[2][q]); a2 += dot4f(u, h0q[q]); u = fetch4(Wh[2][q]); a2 += dot4f(u, h1q[q]); }
        { float4 u = fetch4(Wi[3][q]); a3 += dot4f(u, h0q[q]); u = fetch4(Wh[3][q]); a3 += dot4f(u, h1q[q]); }
      }
#pragma unroll
      for (int m = 1; m < 64; m <<= 1) {
        a0 += __shfl_xor(a0, m, 64);
        a1 += __shfl_xor(a1, m, 64);
        a2 += __shfl_xor(a2, m, 64);
        a3 += __shfl_xor(a3, m, 64);
      }
      c = fsig(a1 + bsum[1]) * c + fsig(a0 + bsum[0]) * ftanh(a2 + bsum[2]);
      float hn = fsig(a3 + bsum[3]) * ftanh(c);
      if (l == 0) {
        astoref(&h1row[(size_t)t * 1024 + hd], hn);
        addrel(&myc[t]);
      }
    }
  }
}

// ---------------- FC + softmax: 16 timesteps per block ----------------
__global__ __launch_bounds__(256) void k_fc(const float* __restrict__ h1row,
                                            const float* __restrict__ fcwT,
                                            const float* __restrict__ fcb,
                                            float* __restrict__ out) {
  __shared__ float smem[16 * 1024];
  const int tid = threadIdx.x;
  const int t0 = blockIdx.x * 16;

  for (int i = 0; i < 64; ++i) {
    int e = tid + 256 * i;
    int tt = e >> 10, k = e & 1023;
    smem[e] = h1row[(size_t)(t0 + tt) * 1024 + k];
  }
  __syncthreads();

  float acc0[16], acc1[16];
#pragma unroll
  for (int tt = 0; tt < 16; ++tt) { acc0[tt] = 0.f; acc1[tt] = 0.f; }

  for (int k0 = 0; k0 < 1024; k0 += 4) {
    float4 w0v, w1v;
    w0v.x = fcwT[(k0 + 0) * 512 + tid];       w1v.x = fcwT[(k0 + 0) * 512 + 256 + tid];
    w0v.y = fcwT[(k0 + 1) * 512 + tid];       w1v.y = fcwT[(k0 + 1) * 512 + 256 + tid];
    w0v.z = fcwT[(k0 + 2) * 512 + tid];       w1v.z = fcwT[(k0 + 2) * 512 + 256 + tid];
    w0v.w = fcwT[(k0 + 3) * 512 + tid];       w1v.w = fcwT[(k0 + 3) * 512 + 256 + tid];
    float4 hv[16];
#pragma unroll
    for (int tt = 0; tt < 16; ++tt) hv[tt] = *(const float4*)&smem[tt * 1024 + k0];
#pragma unroll
    for (int tt = 0; tt < 16; ++tt) {
      acc0[tt] += dot4f(w0v, hv[tt]);
      acc1[tt] += dot4f(w1v, hv[tt]);
    }
  }
  float bb0 = fcb[tid], bb1 = fcb[tid + 256];
  __syncthreads();  // done reading h1 tile; alias smem as logits [16][512]
#pragma unroll
  for (int tt = 0; tt < 16; ++tt) {
    smem[tt * 512 + tid] = acc0[tt] + bb0;
    smem[tt * 512 + 256 + tid] = acc1[tt] + bb1;
  }
  __syncthreads();

  const int wv = tid >> 6, l = tid & 63;
  for (int r = 0; r < 4; ++r) {
    int tt = wv * 4 + r;
    float v[8];
    float mx = -3.4e38f;
#pragma unroll
    for (int m = 0; m < 8; ++m) { v[m] = smem[tt * 512 + m * 64 + l]; mx = fmaxf(mx, v[m]); }
#pragma unroll
    for (int s = 1; s < 64; s <<= 1) mx = fmaxf(mx, __shfl_xor(mx, s, 64));
    float sum = 0.f;
#pragma unroll
    for (int m = 0; m < 8; ++m) { v[m] = expf(v[m] - mx); sum += v[m]; }
#pragma unroll
    for (int s = 1; s < 64; s <<= 1) sum += __shfl_xor(sum, s, 64);
    float inv = 1.0f / sum;
#pragma unroll
    for (int m = 0; m < 8; ++m) out[(size_t)(t0 + tt) * 512 + m * 64 + l] = v[m] * inv;
  }
}

extern "C" void kernel_launch(void* const* d_in, const int* in_sizes, int n_in,
                              void* d_out, int out_size, void* d_ws, size_t ws_size,
                              hipStream_t stream) {
  const float* x    = (const float*)d_in[0];
  const float* Wih0 = (const float*)d_in[1];
  const float* Whh0 = (const float*)d_in[2];
  const float* bih0 = (const float*)d_in[3];
  const float* bhh0 = (const float*)d_in[4];
  const float* Wih1 = (const float*)d_in[5];
  const float* Whh1 = (const float*)d_in[6];
  const float* bih1 = (const float*)d_in[7];
  const float* bhh1 = (const float*)d_in[8];
  const float* h0in = (const float*)d_in[9];
  const float* c0in = (const float*)d_in[10];
  const float* fcw  = (const float*)d_in[11];
  const float* fcb  = (const float*)d_in[12];
  float* out = (float*)d_out;

  // workspace: h0row 16MB | h1row 16MB | cnt 256KB | fcwT 2MB  (~34.3MB)
  float* h0row = (float*)d_ws;
  float* h1row = h0row + (size_t)LSTM_B * 1024;
  u32*   cnt   = (u32*)(h1row + (size_t)LSTM_B * 1024);
  float* fcwT  = (float*)(cnt + (size_t)8 * CSTRIDE);

  hipMemsetAsync(cnt, 0, (size_t)8 * CSTRIDE * sizeof(u32), stream);
  hipLaunchKernelGGL(k_transpose, dim3((512 * 1024) / 256), dim3(256), 0, stream, fcw, fcwT);
  hipLaunchKernelGGL(k_recur, dim3(256), dim3(512), 0, stream,
                     x, Whh0, Wih0, bih0, bhh0, Wih1, Whh1, bih1, bhh1,
                     h0in, c0in, h0row, h1row, cnt);
  hipLaunchKernelGGL(k_fc, dim3(LSTM_B / 16), dim3(256), 0, stream, h1row, fcwT, fcb, out);
}

// Round 7
// 28967.719 us; speedup vs baseline: 9.3186x; 9.3186x over previous
//
#include <hip/hip_runtime.h>

#define LSTM_B   4096
#define LSTM_H   1024
#define LSTM_IN  512
#define LSTM_OUT 512
#define GMIR     (LSTM_B * 32)   // u32 words per gdone mirror (4096 steps x 32 groups)

typedef unsigned long long u64;
typedef unsigned int u32;

__device__ __forceinline__ u64 aload64(u64* p) {
  return __hip_atomic_load(p, __ATOMIC_RELAXED, __HIP_MEMORY_SCOPE_AGENT);
}
__device__ __forceinline__ u32 aload32(u32* p) {
  return __hip_atomic_load(p, __ATOMIC_RELAXED, __HIP_MEMORY_SCOPE_AGENT);
}
__device__ __forceinline__ void astore64(u64* p, u64 v) {
  __hip_atomic_store(p, v, __ATOMIC_RELAXED, __HIP_MEMORY_SCOPE_AGENT);
}
__device__ __forceinline__ void astore32(u32* p, u32 v) {
  __hip_atomic_store(p, v, __ATOMIC_RELAXED, __HIP_MEMORY_SCOPE_AGENT);
}
__device__ __forceinline__ u64 packft(float f, u32 tag) {
  return ((u64)tag << 32) | (u64)__float_as_uint(f);
}
__device__ __forceinline__ float dot4f(float4 a, float4 b) {
  return fmaf(a.x, b.x, fmaf(a.y, b.y, fmaf(a.z, b.z, a.w * b.w)));
}
__device__ __forceinline__ float fsig(float x) {
  return __builtin_amdgcn_rcpf(1.0f + __expf(-x));
}
__device__ __forceinline__ float ftanh(float x) {
  return 1.0f - 2.0f * __builtin_amdgcn_rcpf(1.0f + __expf(2.0f * x));
}

// ---- AGPR parking (proven in R4/R5): weights live in the accumulator file.
__device__ __forceinline__ void park4(float4& a, float4 v) {
  asm volatile("v_accvgpr_write_b32 %0, %4\n\t"
               "v_accvgpr_write_b32 %1, %5\n\t"
               "v_accvgpr_write_b32 %2, %6\n\t"
               "v_accvgpr_write_b32 %3, %7"
               : "=a"(a.x), "=a"(a.y), "=a"(a.z), "=a"(a.w)
               : "v"(v.x), "v"(v.y), "v"(v.z), "v"(v.w));
}
__device__ __forceinline__ float4 fetch4(const float4& a) {
  float4 r;
  asm volatile("v_accvgpr_read_b32 %0, %4\n\t"
               "v_accvgpr_read_b32 %1, %5\n\t"
               "v_accvgpr_read_b32 %2, %6\n\t"
               "v_accvgpr_read_b32 %3, %7"
               : "=v"(r.x), "=v"(r.y), "=v"(r.z), "=v"(r.w)
               : "a"(a.x), "a"(a.y), "a"(a.z), "a"(a.w));
  return r;
}

// LDS flag helpers (workgroup scope)
__device__ __forceinline__ u32 lload(u32* p) {
  return __hip_atomic_load(p, __ATOMIC_ACQUIRE, __HIP_MEMORY_SCOPE_WORKGROUP);
}
__device__ __forceinline__ void lstore(u32* p, u32 v) {
  __hip_atomic_store(p, v, __ATOMIC_RELEASE, __HIP_MEMORY_SCOPE_WORKGROUP);
}

// ---------------- transpose fc_w [512,1024] -> fcwT [1024,512] ----------------
__global__ void k_transpose(const float* __restrict__ w, float* __restrict__ wT) {
  int idx = blockIdx.x * 256 + threadIdx.x;
  int k = idx >> 9;
  int o = idx & 511;
  wT[idx] = w[o * 1024 + k];
}

// ---------------- persistent recurrent kernel ----------------
// 256 blocks x 512 threads, NO per-step barriers. Block bx owns units 4bx..4bx+3.
// Waves 4-7: layer0 (96 wt floats in AGPR). Waves 0-3: layer1 (128 in AGPR).
// Transport: tagged u64 rows h0row/h1row (value+tag stored atomically, 1 writer/slot).
// Completion tree: in blocks with bx%8==0, wave5 polls its group's 32 h0 slots and
// publishes gd0[t*32+g] (x8 mirrors); wave1 ditto for h1 -> gd1. Consumers poll
// 32 u32 words (1 load/lane/round). Rows are bulk-loaded ONCE per block by a
// stager wave (w4: h0 -> h0s[parity], w0: h1 -> h1s) and shared via LDS flags.
// Overwrite safety: h0s double-buffered; w4 additionally bounds L1 lag by
// polling gd1[t-3] before reusing a buffer. All flag spins are monotone >=.
__global__ __launch_bounds__(512)
__attribute__((amdgpu_waves_per_eu(2, 2)))
void k_recur(
    const float* __restrict__ x,
    const float* __restrict__ Whh0, const float* __restrict__ Wih0,
    const float* __restrict__ bih0, const float* __restrict__ bhh0,
    const float* __restrict__ Wih1, const float* __restrict__ Whh1,
    const float* __restrict__ bih1, const float* __restrict__ bhh1,
    const float* __restrict__ h0in, const float* __restrict__ c0in,
    u64* __restrict__ h0row, u64* __restrict__ h1row,
    u32* __restrict__ gd0, u32* __restrict__ gd1)
{
  __shared__ float h0s[2][LSTM_H];
  __shared__ float h1s[LSTM_H];
  __shared__ u32 h0flag, h1flag;

  const int tid = threadIdx.x;
  const int w = tid >> 6, l = tid & 63;
  const int bx = blockIdx.x;
  const int j = w & 3;
  const int hd = 4 * bx + j;
  const bool isagg = (bx & 7) == 0;
  const int g = bx >> 3;
  const u32 mir = (u32)(bx & 7);

  if (tid == 0) { h0flag = 0; h1flag = 0; }
  __syncthreads();   // one-time init barrier only

  if (w >= 4) {
    // ================= layer-0 waves =================
    float4 Whr[4][4], Wxr[4][2];
#pragma unroll
    for (int gg = 0; gg < 4; ++gg) {
#pragma unroll
      for (int q = 0; q < 4; ++q)
        park4(Whr[gg][q], *(const float4*)&Whh0[(size_t)(gg * 1024 + hd) * 1024 + q * 256 + 4 * l]);
#pragma unroll
      for (int q = 0; q < 2; ++q)
        park4(Wxr[gg][q], *(const float4*)&Wih0[(size_t)(gg * 1024 + hd) * 512 + q * 256 + 4 * l]);
    }
    float bsum[4];
#pragma unroll
    for (int gg = 0; gg < 4; ++gg) bsum[gg] = bih0[gg * 1024 + hd] + bhh0[gg * 1024 + hd];
    float c = c0in[hd];

#pragma unroll 1
    for (int t = 0; t < LSTM_B; ++t) {
      float4 xa = *(const float4*)&x[(size_t)t * 512 + 4 * l];
      float4 xb = *(const float4*)&x[(size_t)t * 512 + 256 + 4 * l];
      float4 hq[4];

      if (t == 0) {
#pragma unroll
        for (int q = 0; q < 4; ++q) hq[q] = *(const float4*)&h0in[q * 256 + 4 * l];
      } else if (w == 4) {
        // ---- stager: poll gdone words, bulk-load row t-1, stage to LDS
        const u32 want0 = (u32)t;        // gd0[t-1] holds t
        const u32 want1 = (u32)(t - 2);  // gd1[t-3] holds t-2 (bounds L1 lag)
        u32* p0 = &gd0[(size_t)mir * GMIR + (size_t)(t - 1) * 32];
        u32* p1 = &gd1[(size_t)mir * GMIR + (size_t)(t - 3) * 32];
        for (;;) {
          bool ok;
          if (l < 32)           ok = (aload32(&p0[l]) == want0);
          else if (t >= 3)      ok = (aload32(&p1[l - 32]) == want1);
          else                  ok = true;
          if (__all(ok)) break;
          __builtin_amdgcn_s_sleep(2);
        }
        u64* rp = &h0row[(size_t)(t - 1) * 1024 + 4 * l];
#pragma unroll
        for (int q = 0; q < 4; ++q) {
          u64 v0 = aload64(&rp[q * 256 + 0]);
          u64 v1 = aload64(&rp[q * 256 + 1]);
          u64 v2 = aload64(&rp[q * 256 + 2]);
          u64 v3 = aload64(&rp[q * 256 + 3]);
          float4 f;
          f.x = __uint_as_float((u32)v0); f.y = __uint_as_float((u32)v1);
          f.z = __uint_as_float((u32)v2); f.w = __uint_as_float((u32)v3);
          hq[q] = f;
          *(float4*)&h0s[(t - 1) & 1][q * 256 + 4 * l] = f;
        }
        lstore(&h0flag, (u32)t);
      } else {
        // ---- consumer: LDS flag spin (zero fabric traffic), then ds_read
        while (lload(&h0flag) < (u32)t) __builtin_amdgcn_s_sleep(1);
#pragma unroll
        for (int q = 0; q < 4; ++q) hq[q] = *(const float4*)&h0s[(t - 1) & 1][q * 256 + 4 * l];
      }

      float a0 = 0.f, a1 = 0.f, a2 = 0.f, a3 = 0.f;
#pragma unroll
      for (int q = 0; q < 4; ++q) {
        { float4 u = fetch4(Whr[0][q]); a0 += dot4f(u, hq[q]); }
        { float4 u = fetch4(Whr[1][q]); a1 += dot4f(u, hq[q]); }
        { float4 u = fetch4(Whr[2][q]); a2 += dot4f(u, hq[q]); }
        { float4 u = fetch4(Whr[3][q]); a3 += dot4f(u, hq[q]); }
      }
      { float4 u = fetch4(Wxr[0][0]); a0 += dot4f(u, xa); u = fetch4(Wxr[0][1]); a0 += dot4f(u, xb); }
      { float4 u = fetch4(Wxr[1][0]); a1 += dot4f(u, xa); u = fetch4(Wxr[1][1]); a1 += dot4f(u, xb); }
      { float4 u = fetch4(Wxr[2][0]); a2 += dot4f(u, xa); u = fetch4(Wxr[2][1]); a2 += dot4f(u, xb); }
      { float4 u = fetch4(Wxr[3][0]); a3 += dot4f(u, xa); u = fetch4(Wxr[3][1]); a3 += dot4f(u, xb); }
#pragma unroll
      for (int m = 1; m < 64; m <<= 1) {
        a0 += __shfl_xor(a0, m, 64);
        a1 += __shfl_xor(a1, m, 64);
        a2 += __shfl_xor(a2, m, 64);
        a3 += __shfl_xor(a3, m, 64);
      }
      c = fsig(a1 + bsum[1]) * c + fsig(a0 + bsum[0]) * ftanh(a2 + bsum[2]);
      float hn = fsig(a3 + bsum[3]) * ftanh(c);
      if (l == 0) astore64(&h0row[(size_t)t * 1024 + hd], packft(hn, (u32)(t + 1)));

      if (w == 5 && isagg) {
        // ---- group aggregator for h0 row t: poll 32 tagged slots, publish gd0
        const u32 want = (u32)(t + 1);
        u64* sp = &h0row[(size_t)t * 1024 + 32 * g];
        for (;;) {
          bool ok = (l < 32) ? ((u32)(aload64(&sp[l]) >> 32) == want) : true;
          if (__all(ok)) break;
          __builtin_amdgcn_s_sleep(2);
        }
        if (l < 8) astore32(&gd0[(size_t)l * GMIR + (size_t)t * 32 + g], want);
      }
    }

    // epilogue: stage h0(4095) so layer-1 step 4095 can run (flag 4096)
    if (w == 4) {
      const int t = LSTM_B;  // staging-only iteration
      const u32 want0 = (u32)t;
      const u32 want1 = (u32)(t - 2);
      u32* p0 = &gd0[(size_t)mir * GMIR + (size_t)(t - 1) * 32];
      u32* p1 = &gd1[(size_t)mir * GMIR + (size_t)(t - 3) * 32];
      for (;;) {
        bool ok;
        if (l < 32) ok = (aload32(&p0[l]) == want0);
        else        ok = (aload32(&p1[l - 32]) == want1);
        if (__all(ok)) break;
        __builtin_amdgcn_s_sleep(2);
      }
      u64* rp = &h0row[(size_t)(t - 1) * 1024 + 4 * l];
#pragma unroll
      for (int q = 0; q < 4; ++q) {
        u64 v0 = aload64(&rp[q * 256 + 0]);
        u64 v1 = aload64(&rp[q * 256 + 1]);
        u64 v2 = aload64(&rp[q * 256 + 2]);
        u64 v3 = aload64(&rp[q * 256 + 3]);
        float4 f;
        f.x = __uint_as_float((u32)v0); f.y = __uint_as_float((u32)v1);
        f.z = __uint_as_float((u32)v2); f.w = __uint_as_float((u32)v3);
        *(float4*)&h0s[(t - 1) & 1][q * 256 + 4 * l] = f;
      }
      lstore(&h0flag, (u32)t);
    }
  } else {
    // ================= layer-1 waves =================
    float4 Wi[4][4], Wh[4][4];
#pragma unroll
    for (int gg = 0; gg < 4; ++gg)
#pragma unroll
      for (int q = 0; q < 4; ++q) {
        park4(Wi[gg][q], *(const float4*)&Wih1[(size_t)(gg * 1024 + hd) * 1024 + q * 256 + 4 * l]);
        park4(Wh[gg][q], *(const float4*)&Whh1[(size_t)(gg * 1024 + hd) * 1024 + q * 256 + 4 * l]);
      }
    float bsum[4];
#pragma unroll
    for (int gg = 0; gg < 4; ++gg) bsum[gg] = bih1[gg * 1024 + hd] + bhh1[gg * 1024 + hd];
    float c = c0in[1024 + hd];

#pragma unroll 1
    for (int t = 0; t < LSTM_B; ++t) {
      float4 h1q[4];
      if (t == 0) {
#pragma unroll
        for (int q = 0; q < 4; ++q) h1q[q] = *(const float4*)&h0in[1024 + q * 256 + 4 * l];
      } else if (w == 0) {
        // ---- h1 stager: poll gd1[t-1], bulk-load h1row[t-1], stage to LDS
        const u32 want = (u32)t;  // gd1[t-1] holds t
        u32* p1 = &gd1[(size_t)mir * GMIR + (size_t)(t - 1) * 32];
        for (;;) {
          bool ok = (l < 32) ? (aload32(&p1[l]) == want) : true;
          if (__all(ok)) break;
          __builtin_amdgcn_s_sleep(2);
        }
        u64* rp = &h1row[(size_t)(t - 1) * 1024 + 4 * l];
#pragma unroll
        for (int q = 0; q < 4; ++q) {
          u64 v0 = aload64(&rp[q * 256 + 0]);
          u64 v1 = aload64(&rp[q * 256 + 1]);
          u64 v2 = aload64(&rp[q * 256 + 2]);
          u64 v3 = aload64(&rp[q * 256 + 3]);
          float4 f;
          f.x = __uint_as_float((u32)v0); f.y = __uint_as_float((u32)v1);
          f.z = __uint_as_float((u32)v2); f.w = __uint_as_float((u32)v3);
          h1q[q] = f;
          *(float4*)&h1s[q * 256 + 4 * l] = f;
        }
        lstore(&h1flag, (u32)(t + 1));
      } else {
        while (lload(&h1flag) < (u32)(t + 1)) __builtin_amdgcn_s_sleep(1);
#pragma unroll
        for (int q = 0; q < 4; ++q) h1q[q] = *(const float4*)&h1s[q * 256 + 4 * l];
      }

      // h0(t) via LDS (staged by w4 at its iteration t+1 -> flag t+1)
      while (lload(&h0flag) < (u32)(t + 1)) __builtin_amdgcn_s_sleep(1);
      float4 h0q[4];
#pragma unroll
      for (int q = 0; q < 4; ++q) h0q[q] = *(const float4*)&h0s[t & 1][q * 256 + 4 * l];

      float a0 = 0.f, a1 = 0.f, a2 = 0.f, a3 = 0.f;
#pragma unroll
      for (int q = 0; q < 4; ++q) {
        { float4 u = fetch4(Wi[0][q]); a0 += dot4f(u, h0q[q]); u = fetch4(Wh[0][q]); a0 += dot4f(u, h1q[q]); }
        { float4 u = fetch4(Wi[1][q]); a1 += dot4f(u, h0q[q]); u = fetch4(Wh[1][q]); a1 += dot4f(u, h1q[q]); }
        { float4 u = fetch4(Wi[2][q]); a2 += dot4f(u, h0q[q]); u = fetch4(Wh[2][q]); a2 += dot4f(u, h1q[q]); }
        { float4 u = fetch4(Wi[3][q]); a3 += dot4f(u, h0q[q]); u = fetch4(Wh[3][q]); a3 += dot4f(u, h1q[q]); }
      }
#pragma unroll
      for (int m = 1; m < 64; m <<= 1) {
        a0 += __shfl_xor(a0, m, 64);
        a1 += __shfl_xor(a1, m, 64);
        a2 += __shfl_xor(a2, m, 64);
        a3 += __shfl_xor(a3, m, 64);
      }
      c = fsig(a1 + bsum[1]) * c + fsig(a0 + bsum[0]) * ftanh(a2 + bsum[2]);
      float hn = fsig(a3 + bsum[3]) * ftanh(c);
      if (l == 0) astore64(&h1row[(size_t)t * 1024 + hd], packft(hn, (u32)(t + 1)));

      if (w == 1 && isagg) {
        const u32 want = (u32)(t + 1);
        u64* sp = &h1row[(size_t)t * 1024 + 32 * g];
        for (;;) {
          bool ok = (l < 32) ? ((u32)(aload64(&sp[l]) >> 32) == want) : true;
          if (__all(ok)) break;
          __builtin_amdgcn_s_sleep(2);
        }
        if (l < 8) astore32(&gd1[(size_t)l * GMIR + (size_t)t * 32 + g], want);
      }
    }
  }
}

// ---------------- FC + softmax: 16 timesteps per block ----------------
__global__ __launch_bounds__(256) void k_fc(u64* __restrict__ h1row,
                                            const float* __restrict__ fcwT,
                                            const float* __restrict__ fcb,
                                            float* __restrict__ out) {
  __shared__ float smem[16 * 1024];
  const int tid = threadIdx.x;
  const int t0 = blockIdx.x * 16;

  for (int i = 0; i < 64; ++i) {
    int e = tid + 256 * i;
    int tt = e >> 10, k = e & 1023;
    smem[e] = __uint_as_float((u32)h1row[(size_t)(t0 + tt) * 1024 + k]);
  }
  __syncthreads();

  float acc0[16], acc1[16];
#pragma unroll
  for (int tt = 0; tt < 16; ++tt) { acc0[tt] = 0.f; acc1[tt] = 0.f; }

  for (int k0 = 0; k0 < 1024; k0 += 4) {
    float4 w0v, w1v;
    w0v.x = fcwT[(k0 + 0) * 512 + tid];       w1v.x = fcwT[(k0 + 0) * 512 + 256 + tid];
    w0v.y = fcwT[(k0 + 1) * 512 + tid];       w1v.y = fcwT[(k0 + 1) * 512 + 256 + tid];
    w0v.z = fcwT[(k0 + 2) * 512 + tid];       w1v.z = fcwT[(k0 + 2) * 512 + 256 + tid];
    w0v.w = fcwT[(k0 + 3) * 512 + tid];       w1v.w = fcwT[(k0 + 3) * 512 + 256 + tid];
    float4 hv[16];
#pragma unroll
    for (int tt = 0; tt < 16; ++tt) hv[tt] = *(const float4*)&smem[tt * 1024 + k0];
#pragma unroll
    for (int tt = 0; tt < 16; ++tt) {
      acc0[tt] += dot4f(w0v, hv[tt]);
      acc1[tt] += dot4f(w1v, hv[tt]);
    }
  }
  float bb0 = fcb[tid], bb1 = fcb[tid + 256];
  __syncthreads();
#pragma unroll
  for (int tt = 0; tt < 16; ++tt) {
    smem[tt * 512 + tid] = acc0[tt] + bb0;
    smem[tt * 512 + 256 + tid] = acc1[tt] + bb1;
  }
  __syncthreads();

  const int wv = tid >> 6, l = tid & 63;
  for (int r = 0; r < 4; ++r) {
    int tt = wv * 4 + r;
    float v[8];
    float mx = -3.4e38f;
#pragma unroll
    for (int m = 0; m < 8; ++m) { v[m] = smem[tt * 512 + m * 64 + l]; mx = fmaxf(mx, v[m]); }
#pragma unroll
    for (int s = 1; s < 64; s <<= 1) mx = fmaxf(mx, __shfl_xor(mx, s, 64));
    float sum = 0.f;
#pragma unroll
    for (int m = 0; m < 8; ++m) { v[m] = expf(v[m] - mx); sum += v[m]; }
#pragma unroll
    for (int s = 1; s < 64; s <<= 1) sum += __shfl_xor(sum, s, 64);
    float inv = 1.0f / sum;
#pragma unroll
    for (int m = 0; m < 8; ++m) out[(size_t)(t0 + tt) * 512 + m * 64 + l] = v[m] * inv;
  }
}

extern "C" void kernel_launch(void* const* d_in, const int* in_sizes, int n_in,
                              void* d_out, int out_size, void* d_ws, size_t ws_size,
                              hipStream_t stream) {
  const float* x    = (const float*)d_in[0];
  const float* Wih0 = (const float*)d_in[1];
  const float* Whh0 = (const float*)d_in[2];
  const float* bih0 = (const float*)d_in[3];
  const float* bhh0 = (const float*)d_in[4];
  const float* Wih1 = (const float*)d_in[5];
  const float* Whh1 = (const float*)d_in[6];
  const float* bih1 = (const float*)d_in[7];
  const float* bhh1 = (const float*)d_in[8];
  const float* h0in = (const float*)d_in[9];
  const float* c0in = (const float*)d_in[10];
  const float* fcw  = (const float*)d_in[11];
  const float* fcb  = (const float*)d_in[12];
  float* out = (float*)d_out;

  // ws: h0row 32MB | h1row 32MB | gd0 4MB | gd1 4MB | fcwT 2MB  (~74MB)
  // No memset needed: 0xAA poison never equals any valid tag (1..4096).
  u64* h0row = (u64*)d_ws;
  u64* h1row = h0row + (size_t)LSTM_B * 1024;
  u32* gd0   = (u32*)(h1row + (size_t)LSTM_B * 1024);
  u32* gd1   = gd0 + (size_t)8 * GMIR;
  float* fcwT = (float*)(gd1 + (size_t)8 * GMIR);

  hipLaunchKernelGGL(k_transpose, dim3((512 * 1024) / 256), dim3(256), 0, stream, fcw, fcwT);
  hipLaunchKernelGGL(k_recur, dim3(256), dim3(512), 0, stream,
                     x, Whh0, Wih0, bih0, bhh0, Wih1, Whh1, bih1, bhh1,
                     h0in, c0in, h0row, h1row, gd0, gd1);
  hipLaunchKernelGGL(k_fc, dim3(LSTM_B / 16), dim3(256), 0, stream, h1row, fcwT, fcb, out);
}